// Round 10
// baseline (68.539 us; speedup 1.0000x reference)
//
#include <hip/hip_runtime.h>
#include <hip/hip_bf16.h>
#include <math.h>

// Problem constants (fixed by the reference)
#define BATCH   131072
#define KTOT    512        // D
#define NCOL    64         // S*P
#define THREADS 512        // 8 waves
#define BM      128        // rows per block: 8 waves x 16 rows
#define NMACRO  4          // 4 macro-steps x 128 k
#define GRID    (BATCH / BM)

// ---------------- LDS ----------------
// Phase 1: encW staged as transposed bf16 [col=64][k=512+pad8] -> pitch 520 shorts
#define BW_PITCH 520                       // shorts; 1040 B
#define BW_SHORTS (64 * BW_PITCH)          // 33280 shorts = 66560 B
// Phase 2 overlays (bW dead after K loop) — float view:
#define CS_OFF   0                         // cs^T [32][132]
#define CS_PITCH 132
#define MF_OFF   4224                      // mps_first [4][32]
#define W1_OFF   4352                      // dec_W1 [32][64]
#define B1_OFF   6400
#define W2_OFF   6464
#define B2_OFF   6528
#define ENC0_OFF 6532                      // [128][4]
#define SMEM_BYTES (BW_SHORTS * 2)         // 66560 B (covers overlays: 28176 B)

typedef __attribute__((ext_vector_type(8))) short short8;   // 8 bf16 = 4 VGPRs
typedef __attribute__((ext_vector_type(4))) float f32x4;

__device__ __forceinline__ short f2bf(float f) {            // fp32 -> bf16, RNE
    unsigned u = __float_as_uint(f);
    unsigned r = u + 0x7FFFu + ((u >> 16) & 1u);
    return (short)(r >> 16);
}

__device__ __forceinline__ short8 cvt8(float4 v0, float4 v1) {
    union { short8 s; __hip_bfloat162 h[4]; } u;
    u.h[0] = __float22bfloat162_rn(make_float2(v0.x, v0.y));
    u.h[1] = __float22bfloat162_rn(make_float2(v0.z, v0.w));
    u.h[2] = __float22bfloat162_rn(make_float2(v1.x, v1.y));
    u.h[3] = __float22bfloat162_rn(make_float2(v1.z, v1.w));
    return u.s;
}

// ---- decoder macros (2 rows x 8 cols per thread, named scalars) ----
#define FMA8D(a0, a1, fs) do { \
    a0.x = fmaf(fs, w0.x, a0.x); a0.y = fmaf(fs, w0.y, a0.y); \
    a0.z = fmaf(fs, w0.z, a0.z); a0.w = fmaf(fs, w0.w, a0.w); \
    a1.x = fmaf(fs, w1.x, a1.x); a1.y = fmaf(fs, w1.y, a1.y); \
    a1.z = fmaf(fs, w1.z, a1.z); a1.w = fmaf(fs, w1.w, a1.w); \
} while (0)

#define TILE_STEP2(fbp, wbp, kk) do { \
    const float* _fp = (fbp) + (kk) * CS_PITCH + tr2 * 2; \
    const float* _wp = (wbp) + (kk) * NCOL + tc8 * 8; \
    float f0 = _fp[0]; \
    float f1 = _fp[1]; \
    float4 w0 = *(const float4*)_wp; \
    float4 w1 = *(const float4*)(_wp + 4); \
    FMA8D(d00, d01, f0); FMA8D(d10, d11, f1); \
} while (0)

// ---- K-loop: load a 128-k batch (512B/row, 8 back-to-back float4 per lane) ----
#define LOADBATCH(M) do { \
    const float* _b = fA + (M) * 128; \
    La0 = *(const float4*)(_b +   0); La1 = *(const float4*)(_b +   4); \
    Lb0 = *(const float4*)(_b +  32); Lb1 = *(const float4*)(_b +  36); \
    Lc0 = *(const float4*)(_b +  64); Lc1 = *(const float4*)(_b +  68); \
    Ld0 = *(const float4*)(_b +  96); Ld1 = *(const float4*)(_b + 100); \
} while (0)

#define MFMA_SUBSTEP(AF, S) do { \
    const short* bp = bcol + (S) * 32; \
    short8 b0 = *(const short8*)(bp); \
    short8 b1 = *(const short8*)(bp +  16 * BW_PITCH); \
    short8 b2 = *(const short8*)(bp +  32 * BW_PITCH); \
    short8 b3 = *(const short8*)(bp +  48 * BW_PITCH); \
    c00 = __builtin_amdgcn_mfma_f32_16x16x32_bf16(AF, b0, c00, 0, 0, 0); \
    c01 = __builtin_amdgcn_mfma_f32_16x16x32_bf16(AF, b1, c01, 0, 0, 0); \
    c02 = __builtin_amdgcn_mfma_f32_16x16x32_bf16(AF, b2, c02, 0, 0, 0); \
    c03 = __builtin_amdgcn_mfma_f32_16x16x32_bf16(AF, b3, c03, 0, 0, 0); \
} while (0)

__global__ __launch_bounds__(THREADS)
void mps_fused(const float* __restrict__ feat, const float* __restrict__ encW,
               const float* __restrict__ encB, const float* __restrict__ lng,
               const float* __restrict__ lnb,  const float* __restrict__ mf,
               const float* __restrict__ W1,   const float* __restrict__ b1,
               const float* __restrict__ W2,   const float* __restrict__ b2,
               float* __restrict__ out)
{
    __shared__ __align__(16) char smem_raw[SMEM_BYTES];
    float* smemf = (float*)smem_raw;
    short* smems = (short*)smem_raw;

    const int t    = threadIdx.x;
    const int w    = t >> 6;          // wave 0..7
    const int l    = t & 63;
    const int ln15 = l & 15;
    const int g    = l >> 4;          // 0..3
    const long r0  = (long)blockIdx.x * BM;

    // ---------------- stage encW -> LDS bf16, transposed [col][k] ----------------
    for (int i = t; i < (KTOT * NCOL) / 4; i += THREADS) {
        float4 v = ((const float4*)encW)[i];
        int e = i * 4;
        int k = e >> 6;          // 0..511
        int c = e & 63;          // 0,4,..,60
        smems[(c + 0) * BW_PITCH + k] = f2bf(v.x);
        smems[(c + 1) * BW_PITCH + k] = f2bf(v.y);
        smems[(c + 2) * BW_PITCH + k] = f2bf(v.z);
        smems[(c + 3) * BW_PITCH + k] = f2bf(v.w);
    }
    __syncthreads();

    // ---------------- MFMA K loop: 4 macro-steps, 512B/row contiguous batches ----
    f32x4 c00 = {0.f,0.f,0.f,0.f}, c01 = {0.f,0.f,0.f,0.f};
    f32x4 c02 = {0.f,0.f,0.f,0.f}, c03 = {0.f,0.f,0.f,0.f};

    const float* fA   = feat + (r0 + w * 16 + ln15) * (long)KTOT + g * 8;
    const short* bcol = smems + ln15 * BW_PITCH + g * 8;

    float4 La0, La1, Lb0, Lb1, Lc0, Lc1, Ld0, Ld1;
    LOADBATCH(0);

    #pragma unroll 1
    for (int m = 0; m < NMACRO; ++m) {
        // consume batch into bf16 frags (frees L registers)
        short8 a0 = cvt8(La0, La1);
        short8 a1 = cvt8(Lb0, Lb1);
        short8 a2 = cvt8(Lc0, Lc1);
        short8 a3 = cvt8(Ld0, Ld1);
        // issue next batch immediately (back-to-back 512B/row)
        if (m + 1 < NMACRO) LOADBATCH(m + 1);
        // compute the 4 k-steps of this batch
        MFMA_SUBSTEP(a0, 4 * m + 0);
        MFMA_SUBSTEP(a1, 4 * m + 1);
        MFMA_SUBSTEP(a2, 4 * m + 2);
        MFMA_SUBSTEP(a3, 4 * m + 3);
    }

    __syncthreads();   // all waves done reading bW before overlays are written

    // ---------------- bias + relu + LayerNorm + enc0 write ----------------
    // C/D layout (m89): col = lane&15, row = (lane>>4)*4 + reg
    const float eb0 = encB[ 0 + ln15];
    const float eb1 = encB[16 + ln15];
    const float eb2 = encB[32 + ln15];
    const float eb3 = encB[48 + ln15];
    const float lngv = lng[ln15 & 3];
    const float lnbv = lnb[ln15 & 3];
    const int rowbase = w * 16 + g * 4;

    #define LNROW(I) do { \
        float v0 = fmaxf(c00[I] + eb0, 0.f); \
        float v1 = fmaxf(c01[I] + eb1, 0.f); \
        float v2 = fmaxf(c02[I] + eb2, 0.f); \
        float v3 = fmaxf(c03[I] + eb3, 0.f); \
        float ss = v0 + v1 + v2 + v3; \
        float qq = fmaf(v0, v0, fmaf(v1, v1, fmaf(v2, v2, v3 * v3))); \
        ss += __shfl_xor(ss, 1, 64); ss += __shfl_xor(ss, 2, 64); \
        ss += __shfl_xor(ss, 4, 64); ss += __shfl_xor(ss, 8, 64); \
        qq += __shfl_xor(qq, 1, 64); qq += __shfl_xor(qq, 2, 64); \
        qq += __shfl_xor(qq, 4, 64); qq += __shfl_xor(qq, 8, 64); \
        if (ln15 < 4) { \
            float mu  = ss * 0.015625f; \
            float var = qq * 0.015625f - mu * mu; \
            float rs  = rsqrtf(var + 1e-5f); \
            smemf[ENC0_OFF + (rowbase + (I)) * 4 + ln15] = \
                (v0 - mu) * rs * lngv + lnbv; \
        } \
    } while (0)

    LNROW(0); LNROW(1); LNROW(2); LNROW(3);

    // stage epilogue weights (into dead bW region)
    for (int idx = t; idx < 128; idx += THREADS)  smemf[MF_OFF + idx] = mf[idx];
    for (int idx = t; idx < 2048; idx += THREADS) smemf[W1_OFF + idx] = W1[idx];
    if (t < 64)             smemf[B1_OFF + t]        = b1[t];
    else if (t < 128)       smemf[W2_OFF + (t - 64)] = W2[t - 64];
    else if (t == 128)      smemf[B2_OFF]            = b2[0];
    __syncthreads();

    // ---------------- MPS site-0: cs^T[32][128] (4 threads/row, 8 x each) ----------------
    {
        const int row   = t >> 2;          // 0..127
        const int xbase = (t & 3) * 8;     // 0,8,16,24
        float4 e = *(const float4*)(smemf + ENC0_OFF + row * 4);
        #pragma unroll
        for (int xq = 0; xq < 2; ++xq) {
            float4 m0 = *(const float4*)(smemf + MF_OFF +  0 + xbase + xq * 4);
            float4 m1 = *(const float4*)(smemf + MF_OFF + 32 + xbase + xq * 4);
            float4 m2 = *(const float4*)(smemf + MF_OFF + 64 + xbase + xq * 4);
            float4 m3 = *(const float4*)(smemf + MF_OFF + 96 + xbase + xq * 4);
            float q0 = fmaf(e.x, m0.x, fmaf(e.y, m1.x, fmaf(e.z, m2.x, e.w * m3.x)));
            float q1 = fmaf(e.x, m0.y, fmaf(e.y, m1.y, fmaf(e.z, m2.y, e.w * m3.y)));
            float q2 = fmaf(e.x, m0.z, fmaf(e.y, m1.z, fmaf(e.z, m2.z, e.w * m3.z)));
            float q3 = fmaf(e.x, m0.w, fmaf(e.y, m1.w, fmaf(e.z, m2.w, e.w * m3.w)));
            smemf[CS_OFF + (xbase + xq * 4 + 0) * CS_PITCH + row] = q0;
            smemf[CS_OFF + (xbase + xq * 4 + 1) * CS_PITCH + row] = q1;
            smemf[CS_OFF + (xbase + xq * 4 + 2) * CS_PITCH + row] = q2;
            smemf[CS_OFF + (xbase + xq * 4 + 3) * CS_PITCH + row] = q3;
        }
    }
    __syncthreads();

    // ---------------- decoder GEMM: C2[128][64] = cs @ W1, 2x8 per thread ----------------
    const int tr2 = t >> 3;    // 0..63 : 2 rows each
    const int tc8 = t & 7;     // 0..7  : 8 cols each
    float4 d00, d01, d10, d11;
    d00.x=d00.y=d00.z=d00.w=0.f; d01.x=d01.y=d01.z=d01.w=0.f;
    d10.x=d10.y=d10.z=d10.w=0.f; d11.x=d11.y=d11.z=d11.w=0.f;

    #pragma unroll 4
    for (int kk = 0; kk < 32; ++kk)
        TILE_STEP2(smemf + CS_OFF, smemf + W1_OFF, kk);

    // ---------------- bias + relu + dot(W2) + 8-lane reduce + sigmoid ----------------
    {
        float4 bb0 = *(const float4*)(smemf + B1_OFF + tc8 * 8);
        float4 bb1 = *(const float4*)(smemf + B1_OFF + tc8 * 8 + 4);
        float4 ww0 = *(const float4*)(smemf + W2_OFF + tc8 * 8);
        float4 ww1 = *(const float4*)(smemf + W2_OFF + tc8 * 8 + 4);
        const float b2v = smemf[B2_OFF];
        #define OUTROW2(i, a0, a1) { \
            float z = fmaxf(a0.x + bb0.x, 0.f) * ww0.x; \
            z = fmaf(fmaxf(a0.y + bb0.y, 0.f), ww0.y, z); \
            z = fmaf(fmaxf(a0.z + bb0.z, 0.f), ww0.z, z); \
            z = fmaf(fmaxf(a0.w + bb0.w, 0.f), ww0.w, z); \
            z = fmaf(fmaxf(a1.x + bb1.x, 0.f), ww1.x, z); \
            z = fmaf(fmaxf(a1.y + bb1.y, 0.f), ww1.y, z); \
            z = fmaf(fmaxf(a1.z + bb1.z, 0.f), ww1.z, z); \
            z = fmaf(fmaxf(a1.w + bb1.w, 0.f), ww1.w, z); \
            z += __shfl_xor(z, 1, 64); z += __shfl_xor(z, 2, 64); z += __shfl_xor(z, 4, 64); \
            if (tc8 == 0) out[r0 + tr2 * 2 + (i)] = 1.f / (1.f + expf(-(z + b2v))); }
        OUTROW2(0, d00, d01)
        OUTROW2(1, d10, d11)
    }
}

extern "C" void kernel_launch(void* const* d_in, const int* in_sizes, int n_in,
                              void* d_out, int out_size, void* d_ws, size_t ws_size,
                              hipStream_t stream)
{
    const float* feat = (const float*)d_in[0];   // [B,512]
    const float* encW = (const float*)d_in[1];   // [512,64]
    const float* encB = (const float*)d_in[2];   // [64]
    const float* lng  = (const float*)d_in[3];   // [64] (only 0..3 used)
    const float* lnb  = (const float*)d_in[4];   // [64] (only 0..3 used)
    const float* mf   = (const float*)d_in[5];   // [4,32]
    // d_in[6] = mps_mid, d_in[7] = mps_last : dead code in the reference
    const float* W1   = (const float*)d_in[8];   // [32,64]
    const float* b1   = (const float*)d_in[9];   // [64]
    const float* W2   = (const float*)d_in[10];  // [64,1]
    const float* b2   = (const float*)d_in[11];  // [1]
    float* out = (float*)d_out;

    hipLaunchKernelGGL(mps_fused, dim3(GRID), dim3(THREADS), 0, stream,
                       feat, encW, encB, lng, lnb, mf, W1, b1, W2, b2, out);
}

// Round 11
// 60.117 us; speedup vs baseline: 1.1401x; 1.1401x over previous
//
#include <hip/hip_runtime.h>
#include <hip/hip_bf16.h>
#include <math.h>

// Problem constants (fixed by the reference)
#define BATCH   131072
#define KTOT    512        // D
#define NCOL    64         // S*P
#define THREADS 512        // 8 waves
#define BM      256        // rows per block: 8 waves x 32 rows
#define NKSTEP  16         // 512 / 32 k per MFMA

// ---------------- LDS ----------------
// Phase 1: encW staged as transposed bf16 [col=64][k=512+pad8] -> pitch 520 shorts
#define BW_PITCH 520                       // shorts; 1040 B
#define BW_SHORTS (64 * BW_PITCH)          // 33280 shorts = 66560 B
// Phase 2 overlays (bW dead after K loop) — float view:
#define CS_OFF   0                         // cs^T [32][260]
#define CS_PITCH 260
#define MF_OFF   8320                      // mps_first [4][32]
#define W1_OFF   8448                      // dec_W1 [32][64]
#define B1_OFF   10496
#define W2_OFF   10560
#define B2_OFF   10624
#define ENC0_OFF 10628                     // [256][4]
#define SMEM_BYTES (BW_SHORTS * 2)         // 66560 B (covers overlays: 46608 B)

typedef __attribute__((ext_vector_type(8))) short short8;   // 8 bf16 = 4 VGPRs
typedef __attribute__((ext_vector_type(4))) float f32x4;

__device__ __forceinline__ short f2bf(float f) {            // fp32 -> bf16, RNE
    unsigned u = __float_as_uint(f);
    unsigned r = u + 0x7FFFu + ((u >> 16) & 1u);
    return (short)(r >> 16);
}

__device__ __forceinline__ short8 cvt8(float4 v0, float4 v1) {
    union { short8 s; __hip_bfloat162 h[4]; } u;
    u.h[0] = __float22bfloat162_rn(make_float2(v0.x, v0.y));
    u.h[1] = __float22bfloat162_rn(make_float2(v0.z, v0.w));
    u.h[2] = __float22bfloat162_rn(make_float2(v1.x, v1.y));
    u.h[3] = __float22bfloat162_rn(make_float2(v1.z, v1.w));
    return u.s;
}

// ---- epilogue decoder macros (4 rows x 8 cols per thread, named scalars) ----
#define FMA8D(a0, a1, fs) do { \
    a0.x = fmaf(fs, w0.x, a0.x); a0.y = fmaf(fs, w0.y, a0.y); \
    a0.z = fmaf(fs, w0.z, a0.z); a0.w = fmaf(fs, w0.w, a0.w); \
    a1.x = fmaf(fs, w1.x, a1.x); a1.y = fmaf(fs, w1.y, a1.y); \
    a1.z = fmaf(fs, w1.z, a1.z); a1.w = fmaf(fs, w1.w, a1.w); \
} while (0)

#define TILE_STEP4(fbp, wbp, kk) do { \
    const float* _fp = (fbp) + (kk) * CS_PITCH + tr4 * 4; \
    const float* _wp = (wbp) + (kk) * NCOL + tc8 * 8; \
    float4 f0 = *(const float4*)_fp; \
    float4 w0 = *(const float4*)_wp; \
    float4 w1 = *(const float4*)(_wp + 4); \
    FMA8D(d00, d01, f0.x); FMA8D(d10, d11, f0.y); \
    FMA8D(d20, d21, f0.z); FMA8D(d30, d31, f0.w); \
} while (0)

// ---- K-loop: MFMA group over ready fragments at step S ----
#define MFMA_GROUP(A0, A1, S) do { \
    const short* bp = bcol + (S) * 32; \
    short8 b0 = *(const short8*)(bp); \
    short8 b1 = *(const short8*)(bp +  16 * BW_PITCH); \
    short8 b2 = *(const short8*)(bp +  32 * BW_PITCH); \
    short8 b3 = *(const short8*)(bp +  48 * BW_PITCH); \
    c00 = __builtin_amdgcn_mfma_f32_16x16x32_bf16(A0, b0, c00, 0, 0, 0); \
    c01 = __builtin_amdgcn_mfma_f32_16x16x32_bf16(A0, b1, c01, 0, 0, 0); \
    c02 = __builtin_amdgcn_mfma_f32_16x16x32_bf16(A0, b2, c02, 0, 0, 0); \
    c03 = __builtin_amdgcn_mfma_f32_16x16x32_bf16(A0, b3, c03, 0, 0, 0); \
    c10 = __builtin_amdgcn_mfma_f32_16x16x32_bf16(A1, b0, c10, 0, 0, 0); \
    c11 = __builtin_amdgcn_mfma_f32_16x16x32_bf16(A1, b1, c11, 0, 0, 0); \
    c12 = __builtin_amdgcn_mfma_f32_16x16x32_bf16(A1, b2, c12, 0, 0, 0); \
    c13 = __builtin_amdgcn_mfma_f32_16x16x32_bf16(A1, b3, c13, 0, 0, 0); \
} while (0)

__global__ __launch_bounds__(THREADS)
void mps_fused(const float* __restrict__ feat, const float* __restrict__ encW,
               const float* __restrict__ encB, const float* __restrict__ lng,
               const float* __restrict__ lnb,  const float* __restrict__ mf,
               const float* __restrict__ W1,   const float* __restrict__ b1,
               const float* __restrict__ W2,   const float* __restrict__ b2,
               float* __restrict__ out)
{
    __shared__ __align__(16) char smem_raw[SMEM_BYTES];
    float* smemf = (float*)smem_raw;
    short* smems = (short*)smem_raw;

    const int t    = threadIdx.x;
    const int w    = t >> 6;          // wave 0..7
    const int l    = t & 63;
    const int ln15 = l & 15;
    const int g    = l >> 4;          // 0..3
    const long r0  = (long)blockIdx.x * BM;

    const float* fA0 = feat + (r0 + w * 32 + ln15) * (long)KTOT + g * 8;
    const float* fA1 = fA0 + 16 * KTOT;

    // ---- pre-issue step-0 feature loads: HBM stream starts at kernel entry ----
    float4 px0 = *(const float4*)fA0;
    float4 px1 = *(const float4*)(fA0 + 4);
    float4 py0 = *(const float4*)fA1;
    float4 py1 = *(const float4*)(fA1 + 4);

    // ---------------- stage encW -> LDS bf16, transposed [col][k] ----------------
    for (int i = t; i < (KTOT * NCOL) / 4; i += THREADS) {
        float4 v = ((const float4*)encW)[i];
        int e = i * 4;
        int k = e >> 6;          // 0..511
        int c = e & 63;          // 0,4,..,60
        smems[(c + 0) * BW_PITCH + k] = f2bf(v.x);
        smems[(c + 1) * BW_PITCH + k] = f2bf(v.y);
        smems[(c + 2) * BW_PITCH + k] = f2bf(v.z);
        smems[(c + 3) * BW_PITCH + k] = f2bf(v.w);
    }
    __syncthreads();

    // ---------------- MFMA K loop ----------------
    f32x4 c00 = {0.f,0.f,0.f,0.f}, c01 = {0.f,0.f,0.f,0.f};
    f32x4 c02 = {0.f,0.f,0.f,0.f}, c03 = {0.f,0.f,0.f,0.f};
    f32x4 c10 = {0.f,0.f,0.f,0.f}, c11 = {0.f,0.f,0.f,0.f};
    f32x4 c12 = {0.f,0.f,0.f,0.f}, c13 = {0.f,0.f,0.f,0.f};

    const short* bcol = smems + ln15 * BW_PITCH + g * 8;

    // peeled step 0 (uses preloaded registers)
    {
        short8 a0 = cvt8(px0, px1);
        short8 a1 = cvt8(py0, py1);
        MFMA_GROUP(a0, a1, 0);
    }
    // steps 1..15: exactly the R6 loop body
    for (int s = 1; s < NKSTEP; ++s) {
        const float* pa0 = fA0 + s * 32;
        float4 x0 = *(const float4*)pa0;
        float4 x1 = *(const float4*)(pa0 + 4);
        const float* pa1 = fA1 + s * 32;
        float4 y0 = *(const float4*)pa1;
        float4 y1 = *(const float4*)(pa1 + 4);
        short8 a0 = cvt8(x0, x1);
        short8 a1 = cvt8(y0, y1);
        MFMA_GROUP(a0, a1, s);
    }

    __syncthreads();   // all waves done reading bW before overlays are written

    // ---------------- bias + relu + LayerNorm + enc0 write ----------------
    // C/D layout (m89): col = lane&15, row = (lane>>4)*4 + reg
    const float eb0 = encB[ 0 + ln15];
    const float eb1 = encB[16 + ln15];
    const float eb2 = encB[32 + ln15];
    const float eb3 = encB[48 + ln15];
    const float lngv = lng[ln15 & 3];
    const float lnbv = lnb[ln15 & 3];
    const int rowbase = w * 32 + g * 4;   // + MT*16 + I

    #define LNROW(A0, A1, A2, A3, MT, I) do { \
        float v0 = fmaxf(A0[I] + eb0, 0.f); \
        float v1 = fmaxf(A1[I] + eb1, 0.f); \
        float v2 = fmaxf(A2[I] + eb2, 0.f); \
        float v3 = fmaxf(A3[I] + eb3, 0.f); \
        float ss = v0 + v1 + v2 + v3; \
        float qq = fmaf(v0, v0, fmaf(v1, v1, fmaf(v2, v2, v3 * v3))); \
        ss += __shfl_xor(ss, 1, 64); ss += __shfl_xor(ss, 2, 64); \
        ss += __shfl_xor(ss, 4, 64); ss += __shfl_xor(ss, 8, 64); \
        qq += __shfl_xor(qq, 1, 64); qq += __shfl_xor(qq, 2, 64); \
        qq += __shfl_xor(qq, 4, 64); qq += __shfl_xor(qq, 8, 64); \
        if (ln15 < 4) { \
            float mu  = ss * 0.015625f; \
            float var = qq * 0.015625f - mu * mu; \
            float rs  = rsqrtf(var + 1e-5f); \
            smemf[ENC0_OFF + (rowbase + (MT) * 16 + (I)) * 4 + ln15] = \
                (v0 - mu) * rs * lngv + lnbv; \
        } \
    } while (0)

    LNROW(c00, c01, c02, c03, 0, 0); LNROW(c00, c01, c02, c03, 0, 1);
    LNROW(c00, c01, c02, c03, 0, 2); LNROW(c00, c01, c02, c03, 0, 3);
    LNROW(c10, c11, c12, c13, 1, 0); LNROW(c10, c11, c12, c13, 1, 1);
    LNROW(c10, c11, c12, c13, 1, 2); LNROW(c10, c11, c12, c13, 1, 3);

    // stage epilogue weights (into dead bW region)
    for (int idx = t; idx < 128; idx += THREADS)  smemf[MF_OFF + idx] = mf[idx];
    for (int idx = t; idx < 2048; idx += THREADS) smemf[W1_OFF + idx] = W1[idx];
    if (t < 64)             smemf[B1_OFF + t]        = b1[t];
    else if (t < 128)       smemf[W2_OFF + (t - 64)] = W2[t - 64];
    else if (t == 128)      smemf[B2_OFF]            = b2[0];
    __syncthreads();

    // ---------------- MPS site-0: cs^T[32][256] (2 threads/row, 16 x each) ----------------
    {
        const int row   = t >> 1;
        const int xbase = (t & 1) * 16;
        float4 e = *(const float4*)(smemf + ENC0_OFF + row * 4);
        #pragma unroll
        for (int xq = 0; xq < 4; ++xq) {
            float4 m0 = *(const float4*)(smemf + MF_OFF +  0 + xbase + xq * 4);
            float4 m1 = *(const float4*)(smemf + MF_OFF + 32 + xbase + xq * 4);
            float4 m2 = *(const float4*)(smemf + MF_OFF + 64 + xbase + xq * 4);
            float4 m3 = *(const float4*)(smemf + MF_OFF + 96 + xbase + xq * 4);
            float q0 = fmaf(e.x, m0.x, fmaf(e.y, m1.x, fmaf(e.z, m2.x, e.w * m3.x)));
            float q1 = fmaf(e.x, m0.y, fmaf(e.y, m1.y, fmaf(e.z, m2.y, e.w * m3.y)));
            float q2 = fmaf(e.x, m0.z, fmaf(e.y, m1.z, fmaf(e.z, m2.z, e.w * m3.z)));
            float q3 = fmaf(e.x, m0.w, fmaf(e.y, m1.w, fmaf(e.z, m2.w, e.w * m3.w)));
            smemf[CS_OFF + (xbase + xq * 4 + 0) * CS_PITCH + row] = q0;
            smemf[CS_OFF + (xbase + xq * 4 + 1) * CS_PITCH + row] = q1;
            smemf[CS_OFF + (xbase + xq * 4 + 2) * CS_PITCH + row] = q2;
            smemf[CS_OFF + (xbase + xq * 4 + 3) * CS_PITCH + row] = q3;
        }
    }
    __syncthreads();

    // ---------------- decoder GEMM: C2[256][64] = cs @ W1, 4x8 per thread ----------------
    const int tr4 = t >> 3;    // 0..63 : 4 rows each
    const int tc8 = t & 7;     // 0..7  : 8 cols each
    float4 d00, d01, d10, d11, d20, d21, d30, d31;
    d00.x=d00.y=d00.z=d00.w=0.f; d01.x=d01.y=d01.z=d01.w=0.f;
    d10.x=d10.y=d10.z=d10.w=0.f; d11.x=d11.y=d11.z=d11.w=0.f;
    d20.x=d20.y=d20.z=d20.w=0.f; d21.x=d21.y=d21.z=d21.w=0.f;
    d30.x=d30.y=d30.z=d30.w=0.f; d31.x=d31.y=d31.z=d31.w=0.f;

    #pragma unroll 4
    for (int kk = 0; kk < 32; ++kk)
        TILE_STEP4(smemf + CS_OFF, smemf + W1_OFF, kk);

    // ---------------- bias + relu + dot(W2) + 8-lane reduce + sigmoid ----------------
    {
        float4 bb0 = *(const float4*)(smemf + B1_OFF + tc8 * 8);
        float4 bb1 = *(const float4*)(smemf + B1_OFF + tc8 * 8 + 4);
        float4 ww0 = *(const float4*)(smemf + W2_OFF + tc8 * 8);
        float4 ww1 = *(const float4*)(smemf + W2_OFF + tc8 * 8 + 4);
        const float b2v = smemf[B2_OFF];
        #define OUTROW4(i, a0, a1) { \
            float z = fmaxf(a0.x + bb0.x, 0.f) * ww0.x; \
            z = fmaf(fmaxf(a0.y + bb0.y, 0.f), ww0.y, z); \
            z = fmaf(fmaxf(a0.z + bb0.z, 0.f), ww0.z, z); \
            z = fmaf(fmaxf(a0.w + bb0.w, 0.f), ww0.w, z); \
            z = fmaf(fmaxf(a1.x + bb1.x, 0.f), ww1.x, z); \
            z = fmaf(fmaxf(a1.y + bb1.y, 0.f), ww1.y, z); \
            z = fmaf(fmaxf(a1.z + bb1.z, 0.f), ww1.z, z); \
            z = fmaf(fmaxf(a1.w + bb1.w, 0.f), ww1.w, z); \
            z += __shfl_xor(z, 1, 64); z += __shfl_xor(z, 2, 64); z += __shfl_xor(z, 4, 64); \
            if (tc8 == 0) out[r0 + tr4 * 4 + (i)] = 1.f / (1.f + expf(-(z + b2v))); }
        OUTROW4(0, d00, d01) OUTROW4(1, d10, d11)
        OUTROW4(2, d20, d21) OUTROW4(3, d30, d31)
    }
}

extern "C" void kernel_launch(void* const* d_in, const int* in_sizes, int n_in,
                              void* d_out, int out_size, void* d_ws, size_t ws_size,
                              hipStream_t stream)
{
    const float* feat = (const float*)d_in[0];   // [B,512]
    const float* encW = (const float*)d_in[1];   // [512,64]
    const float* encB = (const float*)d_in[2];   // [64]
    const float* lng  = (const float*)d_in[3];   // [64] (only 0..3 used)
    const float* lnb  = (const float*)d_in[4];   // [64] (only 0..3 used)
    const float* mf   = (const float*)d_in[5];   // [4,32]
    // d_in[6] = mps_mid, d_in[7] = mps_last : dead code in the reference
    const float* W1   = (const float*)d_in[8];   // [32,64]
    const float* b1   = (const float*)d_in[9];   // [64]
    const float* W2   = (const float*)d_in[10];  // [64,1]
    const float* b2   = (const float*)d_in[11];  // [1]
    float* out = (float*)d_out;

    hipLaunchKernelGGL(mps_fused, dim3(BATCH / BM), dim3(THREADS), 0, stream,
                       feat, encW, encB, lng, lnb, mf, W1, b1, W2, b2, out);
}